// Round 6
// baseline (136.437 us; speedup 1.0000x reference)
//
#include <hip/hip_runtime.h>
#include <hip/hip_cooperative_groups.h>
#include <math.h>

namespace cg = cooperative_groups;

#define BLK 256
#define NX 8              // x-points per thread
#define XT 2              // x-tiles: 4096 / (BLK*NX)
#define NPTS 4096
#define YLEN 256          // y-chunk length
#define CCH (NPTS / YLEN) // 16 chunks
#define UNITS 65536       // 2 dirs * 8 batches * 4096 points

// ---- shared compute core: per-chunk partial mins via
// dist = 2*(x2/2 + min_y(y2/2 - x.y)), y staged in LDS as
// (y0,y1,y2,||y||^2/2); broadcast reads, 0 bank conflicts. ----
__device__ __forceinline__ void partial_core(
    const float* __restrict__ xs, const float* __restrict__ ys,
    float* __restrict__ partial, float4* sh,
    int c, int xt, int b, int dir)
{
  // Stage y chunk (256 y's, one per thread).
  {
    int j = threadIdx.x;
    float y0 = ys[(c * YLEN + j) * 3 + 0];
    float y1 = ys[(c * YLEN + j) * 3 + 1];
    float y2 = ys[(c * YLEN + j) * 3 + 2];
    sh[j] = make_float4(y0, y1, y2, 0.5f * (y0 * y0 + y1 * y1 + y2 * y2));
  }
  __syncthreads();

  // This thread's 8 x-points (24 contiguous floats, 16B-aligned).
  int x0i = xt * (BLK * NX) + threadIdx.x * NX;
  float xf[NX * 3];
  {
    const float4* xp = reinterpret_cast<const float4*>(xs + x0i * 3);
    #pragma unroll
    for (int i = 0; i < 6; ++i) {
      float4 p = xp[i];
      xf[i * 4 + 0] = p.x; xf[i * 4 + 1] = p.y;
      xf[i * 4 + 2] = p.z; xf[i * 4 + 3] = p.w;
    }
  }
  float n0[NX], n1[NX], n2[NX], x2h[NX], gm[NX];
  #pragma unroll
  for (int k = 0; k < NX; ++k) {
    float a = xf[k * 3 + 0], bb = xf[k * 3 + 1], cc = xf[k * 3 + 2];
    n0[k] = -a; n1[k] = -bb; n2[k] = -cc;
    x2h[k] = 0.5f * (a * a + bb * bb + cc * cc);
    gm[k] = __builtin_inff();
  }

  // Per 4 y's x 8 x's: 12 FMA + 2 v_min3 per k.
  #pragma unroll 4
  for (int j = 0; j < YLEN; j += 4) {
    float4 p0 = sh[j], p1 = sh[j + 1], p2 = sh[j + 2], p3 = sh[j + 3];
    #pragma unroll
    for (int k = 0; k < NX; ++k) {
      float ga = fmaf(n0[k], p0.x, fmaf(n1[k], p0.y, fmaf(n2[k], p0.z, p0.w)));
      float gb = fmaf(n0[k], p1.x, fmaf(n1[k], p1.y, fmaf(n2[k], p1.z, p1.w)));
      float gc = fmaf(n0[k], p2.x, fmaf(n1[k], p2.y, fmaf(n2[k], p2.z, p2.w)));
      float gd = fmaf(n0[k], p3.x, fmaf(n1[k], p3.y, fmaf(n2[k], p3.z, p3.w)));
      float m  = fminf(fminf(ga, gb), gc);       // v_min3
      gm[k] = fminf(fminf(m, gd), gm[k]);        // v_min3
    }
  }

  // Plain float4 stores (NO data atomics — R3: device-scope atomicMin
  // writes through to HBM at 32B/op, 67 MB of traffic).
  float* dst = partial + (size_t)c * UNITS + dir * 32768 + b * 4096 + x0i;
  float4* d4 = reinterpret_cast<float4*>(dst);
  d4[0] = make_float4(2.0f * (x2h[0] + gm[0]), 2.0f * (x2h[1] + gm[1]),
                      2.0f * (x2h[2] + gm[2]), 2.0f * (x2h[3] + gm[3]));
  d4[1] = make_float4(2.0f * (x2h[4] + gm[4]), 2.0f * (x2h[5] + gm[5]),
                      2.0f * (x2h[6] + gm[6]), 2.0f * (x2h[7] + gm[7]));
}

// ---- fused cooperative kernel: partials -> grid.sync -> 16 finalizer
// blocks (one per (dir,b) bucket) min across chunks + mean -> out. ----
__global__ __launch_bounds__(BLK, 2) void chamfer_fused_kernel(
    const float* __restrict__ X, const float* __restrict__ Y,
    float* __restrict__ partial, float* __restrict__ out)
{
  __shared__ float4 sh[YLEN];

  int lin = blockIdx.x;
  int c   = lin % CCH; lin /= CCH;
  int xt  = lin % XT;  lin /= XT;
  int b   = lin & 7;
  int dir = lin >> 3;

  const float* xs = (dir ? Y : X) + b * (NPTS * 3);
  const float* ys = (dir ? X : Y) + b * (NPTS * 3);

  if (blockIdx.x == 0 && threadIdx.x < 8) out[threadIdx.x] = 0.0f;

  partial_core(xs, ys, partial, sh, c, xt, b, dir);

  cg::this_grid().sync();   // release/acquire across the grid

  if (blockIdx.x >= 16) return;

  // Finalizer: bucket = blockIdx.x; thread handles 16 contiguous x-pts.
  int fdir = blockIdx.x >> 3;
  int fb   = blockIdx.x & 7;
  int base = fdir * 32768 + fb * 4096 + threadIdx.x * 16;
  float4 m0 = make_float4(__builtin_inff(), __builtin_inff(),
                          __builtin_inff(), __builtin_inff());
  float4 m1 = m0, m2 = m0, m3 = m0;
  #pragma unroll
  for (int cc = 0; cc < CCH; ++cc) {
    const float4* p = reinterpret_cast<const float4*>(
        partial + (size_t)cc * UNITS + base);
    float4 a0 = p[0], a1 = p[1], a2 = p[2], a3 = p[3];
    m0.x = fminf(m0.x, a0.x); m0.y = fminf(m0.y, a0.y);
    m0.z = fminf(m0.z, a0.z); m0.w = fminf(m0.w, a0.w);
    m1.x = fminf(m1.x, a1.x); m1.y = fminf(m1.y, a1.y);
    m1.z = fminf(m1.z, a1.z); m1.w = fminf(m1.w, a1.w);
    m2.x = fminf(m2.x, a2.x); m2.y = fminf(m2.y, a2.y);
    m2.z = fminf(m2.z, a2.z); m2.w = fminf(m2.w, a2.w);
    m3.x = fminf(m3.x, a3.x); m3.y = fminf(m3.y, a3.y);
    m3.z = fminf(m3.z, a3.z); m3.w = fminf(m3.w, a3.w);
  }
  float s = (m0.x + m0.y + m0.z + m0.w) + (m1.x + m1.y + m1.z + m1.w)
          + (m2.x + m2.y + m2.z + m2.w) + (m3.x + m3.y + m3.z + m3.w);
  #pragma unroll
  for (int off = 32; off > 0; off >>= 1) s += __shfl_down(s, off, 64);
  __syncthreads();                       // sh no longer needed; reuse
  float* red = reinterpret_cast<float*>(sh);
  if ((threadIdx.x & 63) == 0) red[threadIdx.x >> 6] = s;
  __syncthreads();
  if (threadIdx.x == 0) {
    float t = red[0] + red[1] + red[2] + red[3];
    atomicAdd(&out[fb], t * (1.0f / 4096.0f));
  }
}

// ---- fallback two-kernel path (R5, proven) ----
__global__ __launch_bounds__(BLK, 2) void chamfer_partial_kernel(
    const float* __restrict__ X, const float* __restrict__ Y,
    float* __restrict__ partial, float* __restrict__ out)
{
  __shared__ float4 sh[YLEN];
  int lin = blockIdx.x;
  int c   = lin % CCH; lin /= CCH;
  int xt  = lin % XT;  lin /= XT;
  int b   = lin & 7;
  int dir = lin >> 3;
  const float* xs = (dir ? Y : X) + b * (NPTS * 3);
  const float* ys = (dir ? X : Y) + b * (NPTS * 3);
  if (blockIdx.x == 0 && threadIdx.x < 8) out[threadIdx.x] = 0.0f;
  partial_core(xs, ys, partial, sh, c, xt, b, dir);
}

__global__ __launch_bounds__(BLK, 4) void chamfer_reduce_kernel(
    const float* __restrict__ partial, float* __restrict__ out)
{
  int b = blockIdx.x >> 5;
  int s = blockIdx.x & 31;
  int i = s * BLK + threadIdx.x;
  int dir = i >> 12;
  int xi  = i & 4095;
  int unit = dir * 32768 + b * 4096 + xi;
  float v0 = __builtin_inff(), v1 = v0, v2 = v0, v3 = v0;
  float v4 = v0, v5 = v0, v6 = v0, v7 = v0;
  #pragma unroll
  for (int c = 0; c < CCH; c += 8) {
    v0 = fminf(v0, partial[(size_t)(c + 0) * UNITS + unit]);
    v1 = fminf(v1, partial[(size_t)(c + 1) * UNITS + unit]);
    v2 = fminf(v2, partial[(size_t)(c + 2) * UNITS + unit]);
    v3 = fminf(v3, partial[(size_t)(c + 3) * UNITS + unit]);
    v4 = fminf(v4, partial[(size_t)(c + 4) * UNITS + unit]);
    v5 = fminf(v5, partial[(size_t)(c + 5) * UNITS + unit]);
    v6 = fminf(v6, partial[(size_t)(c + 6) * UNITS + unit]);
    v7 = fminf(v7, partial[(size_t)(c + 7) * UNITS + unit]);
  }
  float v = fminf(fminf(fminf(v0, v1), fminf(v2, v3)),
                  fminf(fminf(v4, v5), fminf(v6, v7)));
  #pragma unroll
  for (int off = 32; off > 0; off >>= 1) v += __shfl_down(v, off, 64);
  __shared__ float wsum[BLK / 64];
  if ((threadIdx.x & 63) == 0) wsum[threadIdx.x >> 6] = v;
  __syncthreads();
  if (threadIdx.x == 0) {
    float t = wsum[0] + wsum[1] + wsum[2] + wsum[3];
    atomicAdd(&out[b], t * (1.0f / 4096.0f));
  }
}

// ---- fallback (workspace too small): direct, no workspace ----
__global__ __launch_bounds__(BLK, 2) void chamfer_direct_kernel(
    const float* __restrict__ X, const float* __restrict__ Y,
    float* __restrict__ out)
{
  extern __shared__ float4 shd[];
  int lin = blockIdx.x;
  int xt  = lin & 1;  lin >>= 1;
  int b   = lin & 7;
  int dir = lin >> 3;
  const float* xs = (dir ? Y : X) + b * (NPTS * 3);
  const float* ys = (dir ? X : Y) + b * (NPTS * 3);
  for (int j = threadIdx.x; j < NPTS; j += BLK) {
    float y0 = ys[j * 3 + 0], y1 = ys[j * 3 + 1], y2 = ys[j * 3 + 2];
    shd[j] = make_float4(y0, y1, y2, 0.5f * (y0 * y0 + y1 * y1 + y2 * y2));
  }
  __syncthreads();
  int x0i = xt * (BLK * 8) + threadIdx.x * 8;
  float xf[24];
  const float4* xp = reinterpret_cast<const float4*>(xs + x0i * 3);
  #pragma unroll
  for (int i = 0; i < 6; ++i) {
    float4 p = xp[i];
    xf[i * 4 + 0] = p.x; xf[i * 4 + 1] = p.y;
    xf[i * 4 + 2] = p.z; xf[i * 4 + 3] = p.w;
  }
  float n0[8], n1[8], n2[8], x2h[8], gm[8];
  #pragma unroll
  for (int k = 0; k < 8; ++k) {
    float a = xf[k * 3 + 0], bb = xf[k * 3 + 1], cc = xf[k * 3 + 2];
    n0[k] = -a; n1[k] = -bb; n2[k] = -cc;
    x2h[k] = 0.5f * (a * a + bb * bb + cc * cc);
    gm[k] = __builtin_inff();
  }
  for (int j = 0; j < NPTS; j += 4) {
    float4 p0 = shd[j], p1 = shd[j + 1], p2 = shd[j + 2], p3 = shd[j + 3];
    #pragma unroll
    for (int k = 0; k < 8; ++k) {
      float ga = fmaf(n0[k], p0.x, fmaf(n1[k], p0.y, fmaf(n2[k], p0.z, p0.w)));
      float gb = fmaf(n0[k], p1.x, fmaf(n1[k], p1.y, fmaf(n2[k], p1.z, p1.w)));
      float gc = fmaf(n0[k], p2.x, fmaf(n1[k], p2.y, fmaf(n2[k], p2.z, p2.w)));
      float gd = fmaf(n0[k], p3.x, fmaf(n1[k], p3.y, fmaf(n2[k], p3.z, p3.w)));
      float m  = fminf(fminf(ga, gb), gc);
      gm[k] = fminf(fminf(m, gd), gm[k]);
    }
  }
  float v = 0.0f;
  #pragma unroll
  for (int k = 0; k < 8; ++k) v += 2.0f * (x2h[k] + gm[k]);
  #pragma unroll
  for (int off = 32; off > 0; off >>= 1) v += __shfl_down(v, off, 64);
  __syncthreads();
  float* red = reinterpret_cast<float*>(shd);
  if ((threadIdx.x & 63) == 0) red[threadIdx.x >> 6] = v;
  __syncthreads();
  if (threadIdx.x == 0) {
    float s = red[0] + red[1] + red[2] + red[3];
    atomicAdd(&out[b], s * (1.0f / 4096.0f));
  }
}

__global__ void zero_out_kernel(float* out)
{
  if (threadIdx.x < 8) out[threadIdx.x] = 0.0f;
}

extern "C" void kernel_launch(void* const* d_in, const int* in_sizes, int n_in,
                              void* d_out, int out_size, void* d_ws, size_t ws_size,
                              hipStream_t stream)
{
  const float* X = (const float*)d_in[0];
  const float* Y = (const float*)d_in[1];
  float* out = (float*)d_out;

  if (ws_size >= (size_t)CCH * UNITS * sizeof(float)) {
    float* ws = (float*)d_ws;
    void* args[] = {(void*)&X, (void*)&Y, (void*)&ws, (void*)&out};
    hipError_t err = hipLaunchCooperativeKernel(
        (const void*)chamfer_fused_kernel, dim3(2 * 8 * XT * CCH), dim3(BLK),
        args, 0, stream);
    if (err != hipSuccess) {
      // Fallback: proven R5 two-kernel path.
      chamfer_partial_kernel<<<2 * 8 * XT * CCH, BLK, 0, stream>>>(
          X, Y, ws, out);
      chamfer_reduce_kernel<<<256, BLK, 0, stream>>>(ws, out);
    }
  } else {
    zero_out_kernel<<<1, 64, 0, stream>>>(out);
    chamfer_direct_kernel<<<2 * 8 * 2, BLK, NPTS * sizeof(float4), stream>>>(
        X, Y, out);
  }
}

// Round 7
// 80.686 us; speedup vs baseline: 1.6910x; 1.6910x over previous
//
#include <hip/hip_runtime.h>
#include <math.h>

#define BLK 256
#define NX 8              // x-points per thread
#define XT 2              // x-tiles: 4096 / (BLK*NX)
#define NPTS 4096
#define YLEN 256          // y-chunk length
#define CCH (NPTS / YLEN) // 16 chunks -> grid 512 -> 2 blocks/CU
#define UNITS 65536       // 2 dirs * 8 batches * 4096 points

// Kernel 1: per (dir, batch, x-tile, y-chunk) block compute per-x-point min
// over the y-chunk of ||x-y||^2 via dist = 2*(x2/2 + min_y(y2/2 - x.y)).
// y staged in LDS as (y0,y1,y2,||y||^2/2); broadcast reads, 0 bank conflicts.
// Plain float4 partial stores. Design notes from this session:
//  - R3: device-scope atomicMin writes through to HBM at 32B/op (67 MB) — never.
//  - R6: cg::grid().sync() costs ~50 us on a 512-block grid — two-kernel
//    pipeline is the cheap sync primitive.
//  - R1/R2/R4: NX=8/16, C=16/32, explicit prefetch — all within noise; k1 is
//    at its practical floor (~15 us vs 12 us VALU arithmetic floor).
__global__ __launch_bounds__(BLK, 2) void chamfer_partial_kernel(
    const float* __restrict__ X, const float* __restrict__ Y,
    float* __restrict__ partial, float* __restrict__ out)
{
  __shared__ float4 sh[YLEN];

  int lin = blockIdx.x;
  int c   = lin % CCH; lin /= CCH;
  int xt  = lin % XT;  lin /= XT;
  int b   = lin & 7;
  int dir = lin >> 3;

  const float* xs = (dir ? Y : X) + b * (NPTS * 3);
  const float* ys = (dir ? X : Y) + b * (NPTS * 3);

  // Zero d_out (re-poisoned before every launch); kernel 2 runs strictly
  // after this dispatch on the stream.
  if (blockIdx.x == 0 && threadIdx.x < 8) out[threadIdx.x] = 0.0f;

  // Stage y chunk (256 y's, one per thread).
  {
    int j = threadIdx.x;
    float y0 = ys[(c * YLEN + j) * 3 + 0];
    float y1 = ys[(c * YLEN + j) * 3 + 1];
    float y2 = ys[(c * YLEN + j) * 3 + 2];
    sh[j] = make_float4(y0, y1, y2, 0.5f * (y0 * y0 + y1 * y1 + y2 * y2));
  }
  __syncthreads();

  // This thread's 8 x-points (24 contiguous floats, 16B-aligned).
  int x0i = xt * (BLK * NX) + threadIdx.x * NX;
  float xf[NX * 3];
  {
    const float4* xp = reinterpret_cast<const float4*>(xs + x0i * 3);
    #pragma unroll
    for (int i = 0; i < 6; ++i) {
      float4 p = xp[i];
      xf[i * 4 + 0] = p.x; xf[i * 4 + 1] = p.y;
      xf[i * 4 + 2] = p.z; xf[i * 4 + 3] = p.w;
    }
  }
  float n0[NX], n1[NX], n2[NX], x2h[NX], gm[NX];
  #pragma unroll
  for (int k = 0; k < NX; ++k) {
    float a = xf[k * 3 + 0], bb = xf[k * 3 + 1], cc = xf[k * 3 + 2];
    n0[k] = -a; n1[k] = -bb; n2[k] = -cc;
    x2h[k] = 0.5f * (a * a + bb * bb + cc * cc);
    gm[k] = __builtin_inff();
  }

  // Per 4 y's x 8 x's: 12 FMA + 2 v_min3 per k.
  #pragma unroll 4
  for (int j = 0; j < YLEN; j += 4) {
    float4 p0 = sh[j], p1 = sh[j + 1], p2 = sh[j + 2], p3 = sh[j + 3];
    #pragma unroll
    for (int k = 0; k < NX; ++k) {
      float ga = fmaf(n0[k], p0.x, fmaf(n1[k], p0.y, fmaf(n2[k], p0.z, p0.w)));
      float gb = fmaf(n0[k], p1.x, fmaf(n1[k], p1.y, fmaf(n2[k], p1.z, p1.w)));
      float gc = fmaf(n0[k], p2.x, fmaf(n1[k], p2.y, fmaf(n2[k], p2.z, p2.w)));
      float gd = fmaf(n0[k], p3.x, fmaf(n1[k], p3.y, fmaf(n2[k], p3.z, p3.w)));
      float m  = fminf(fminf(ga, gb), gc);       // v_min3
      gm[k] = fminf(fminf(m, gd), gm[k]);        // v_min3
    }
  }

  float* dst = partial + (size_t)c * UNITS + dir * 32768 + b * 4096 + x0i;
  float4* d4 = reinterpret_cast<float4*>(dst);
  d4[0] = make_float4(2.0f * (x2h[0] + gm[0]), 2.0f * (x2h[1] + gm[1]),
                      2.0f * (x2h[2] + gm[2]), 2.0f * (x2h[3] + gm[3]));
  d4[1] = make_float4(2.0f * (x2h[4] + gm[4]), 2.0f * (x2h[5] + gm[5]),
                      2.0f * (x2h[6] + gm[6]), 2.0f * (x2h[7] + gm[7]));
}

// Kernel 2: min across 16 chunks per point (4 MB, L2-resident), block-reduce
// sums, one atomicAdd per block into out[b].
__global__ __launch_bounds__(BLK, 4) void chamfer_reduce_kernel(
    const float* __restrict__ partial, float* __restrict__ out)
{
  int b = blockIdx.x >> 5;
  int s = blockIdx.x & 31;
  int i = s * BLK + threadIdx.x;   // 0..8191 within batch (both directions)
  int dir = i >> 12;
  int xi  = i & 4095;
  int unit = dir * 32768 + b * 4096 + xi;
  // 8 independent min chains: 2 serial latency rounds over 16 chunks.
  float v0 = __builtin_inff(), v1 = v0, v2 = v0, v3 = v0;
  float v4 = v0, v5 = v0, v6 = v0, v7 = v0;
  #pragma unroll
  for (int c = 0; c < CCH; c += 8) {
    v0 = fminf(v0, partial[(size_t)(c + 0) * UNITS + unit]);
    v1 = fminf(v1, partial[(size_t)(c + 1) * UNITS + unit]);
    v2 = fminf(v2, partial[(size_t)(c + 2) * UNITS + unit]);
    v3 = fminf(v3, partial[(size_t)(c + 3) * UNITS + unit]);
    v4 = fminf(v4, partial[(size_t)(c + 4) * UNITS + unit]);
    v5 = fminf(v5, partial[(size_t)(c + 5) * UNITS + unit]);
    v6 = fminf(v6, partial[(size_t)(c + 6) * UNITS + unit]);
    v7 = fminf(v7, partial[(size_t)(c + 7) * UNITS + unit]);
  }
  float v = fminf(fminf(fminf(v0, v1), fminf(v2, v3)),
                  fminf(fminf(v4, v5), fminf(v6, v7)));
  #pragma unroll
  for (int off = 32; off > 0; off >>= 1) v += __shfl_down(v, off, 64);
  __shared__ float wsum[BLK / 64];
  if ((threadIdx.x & 63) == 0) wsum[threadIdx.x >> 6] = v;
  __syncthreads();
  if (threadIdx.x == 0) {
    float t = wsum[0] + wsum[1] + wsum[2] + wsum[3];
    atomicAdd(&out[b], t * (1.0f / 4096.0f));
  }
}

// Fallback (workspace too small): full y range per block, direct reduction.
__global__ __launch_bounds__(BLK, 2) void chamfer_direct_kernel(
    const float* __restrict__ X, const float* __restrict__ Y,
    float* __restrict__ out)
{
  extern __shared__ float4 shd[];
  int lin = blockIdx.x;
  int xt  = lin & 1;  lin >>= 1;
  int b   = lin & 7;
  int dir = lin >> 3;
  const float* xs = (dir ? Y : X) + b * (NPTS * 3);
  const float* ys = (dir ? X : Y) + b * (NPTS * 3);

  for (int j = threadIdx.x; j < NPTS; j += BLK) {
    float y0 = ys[j * 3 + 0], y1 = ys[j * 3 + 1], y2 = ys[j * 3 + 2];
    shd[j] = make_float4(y0, y1, y2, 0.5f * (y0 * y0 + y1 * y1 + y2 * y2));
  }
  __syncthreads();

  int x0i = xt * (BLK * 8) + threadIdx.x * 8;
  float xf[24];
  const float4* xp = reinterpret_cast<const float4*>(xs + x0i * 3);
  #pragma unroll
  for (int i = 0; i < 6; ++i) {
    float4 p = xp[i];
    xf[i * 4 + 0] = p.x; xf[i * 4 + 1] = p.y;
    xf[i * 4 + 2] = p.z; xf[i * 4 + 3] = p.w;
  }
  float n0[8], n1[8], n2[8], x2h[8], gm[8];
  #pragma unroll
  for (int k = 0; k < 8; ++k) {
    float a = xf[k * 3 + 0], bb = xf[k * 3 + 1], cc = xf[k * 3 + 2];
    n0[k] = -a; n1[k] = -bb; n2[k] = -cc;
    x2h[k] = 0.5f * (a * a + bb * bb + cc * cc);
    gm[k] = __builtin_inff();
  }
  for (int j = 0; j < NPTS; j += 4) {
    float4 p0 = shd[j], p1 = shd[j + 1], p2 = shd[j + 2], p3 = shd[j + 3];
    #pragma unroll
    for (int k = 0; k < 8; ++k) {
      float ga = fmaf(n0[k], p0.x, fmaf(n1[k], p0.y, fmaf(n2[k], p0.z, p0.w)));
      float gb = fmaf(n0[k], p1.x, fmaf(n1[k], p1.y, fmaf(n2[k], p1.z, p1.w)));
      float gc = fmaf(n0[k], p2.x, fmaf(n1[k], p2.y, fmaf(n2[k], p2.z, p2.w)));
      float gd = fmaf(n0[k], p3.x, fmaf(n1[k], p3.y, fmaf(n2[k], p3.z, p3.w)));
      float m  = fminf(fminf(ga, gb), gc);
      gm[k] = fminf(fminf(m, gd), gm[k]);
    }
  }
  float v = 0.0f;
  #pragma unroll
  for (int k = 0; k < 8; ++k) v += 2.0f * (x2h[k] + gm[k]);
  #pragma unroll
  for (int off = 32; off > 0; off >>= 1) v += __shfl_down(v, off, 64);
  __syncthreads();
  float* red = reinterpret_cast<float*>(shd);
  if ((threadIdx.x & 63) == 0) red[threadIdx.x >> 6] = v;
  __syncthreads();
  if (threadIdx.x == 0) {
    float s = red[0] + red[1] + red[2] + red[3];
    atomicAdd(&out[b], s * (1.0f / 4096.0f));
  }
}

__global__ void zero_out_kernel(float* out)
{
  if (threadIdx.x < 8) out[threadIdx.x] = 0.0f;
}

extern "C" void kernel_launch(void* const* d_in, const int* in_sizes, int n_in,
                              void* d_out, int out_size, void* d_ws, size_t ws_size,
                              hipStream_t stream)
{
  const float* X = (const float*)d_in[0];
  const float* Y = (const float*)d_in[1];
  float* out = (float*)d_out;

  if (ws_size >= (size_t)CCH * UNITS * sizeof(float)) {
    // C=16, XT=2, YLEN=256: grid 512 -> 2 blocks/CU; partials 4 MB.
    chamfer_partial_kernel<<<2 * 8 * XT * CCH, BLK, 0, stream>>>(
        X, Y, (float*)d_ws, out);
    chamfer_reduce_kernel<<<256, BLK, 0, stream>>>((const float*)d_ws, out);
  } else {
    zero_out_kernel<<<1, 64, 0, stream>>>(out);
    chamfer_direct_kernel<<<2 * 8 * 2, BLK, NPTS * sizeof(float4), stream>>>(
        X, Y, out);
  }
}